// Round 20
// baseline (574.958 us; speedup 1.0000x reference)
//
#include <hip/hip_runtime.h>
#include <math.h>

// QLinear via int8: y = (sum_k xq[r][k]*Wq[c][k]) * sx[r] * scale[c]
// 4 small independent blocks/CU (4 waves each): narrow sync domains fill
// each other's barrier/drain gaps (extends the R11->R12 mechanism).
#define M_DIM 8192
#define N_DIM 11008
#define K_DIM 4096

#define BM 128
#define BN 128
#define BKB 64                     // K-bytes per tile (64 i8)
#define NT (K_DIM / BKB)           // 64
#define NBN (N_DIM / BN)           // 86
#define NWG ((M_DIM / BM) * NBN)   // 64*86 = 5504 (divisible by 8)

// LDS per buffer: A 128x64B = 8 KiB, B 128x64B = 8 KiB -> 16 KiB; x2 = 32 KiB.
// 4 blocks/CU (128 KiB LDS, 16 waves, 4 waves/SIMD).
#define BUF_STRIDE 16384
#define B_OFF 8192

typedef int int4v __attribute__((ext_vector_type(4)));
typedef int int16v __attribute__((ext_vector_type(16)));

__device__ __forceinline__ void async_copy16(const void* g, void* l) {
  __builtin_amdgcn_global_load_lds(
      (const __attribute__((address_space(1))) void*)g,
      (__attribute__((address_space(3))) void*)l, 16, 0, 0);
}

// ---- x quantization: one block per row; per-row absmax -> i8 ----
__global__ __launch_bounds__(256) void quant_x(const float* __restrict__ x,
                                               signed char* __restrict__ xq,
                                               float* __restrict__ sx) {
  __shared__ float wred[4];
  const int row = blockIdx.x;
  const int tid = threadIdx.x;
  const float4* src = (const float4*)(x + (size_t)row * K_DIM) + tid * 4;
  float4 v0 = src[0], v1 = src[1], v2 = src[2], v3 = src[3];

  float m = 0.f;
#define MX4(V) m = fmaxf(m, fmaxf(fmaxf(fabsf(V.x), fabsf(V.y)), fmaxf(fabsf(V.z), fabsf(V.w))))
  MX4(v0); MX4(v1); MX4(v2); MX4(v3);
#undef MX4
#pragma unroll
  for (int off = 32; off >= 1; off >>= 1)
    m = fmaxf(m, __shfl_xor(m, off, 64));
  if ((tid & 63) == 0) wred[tid >> 6] = m;
  __syncthreads();
  float smax = fmaxf(fmaxf(wred[0], wred[1]), fmaxf(wred[2], wred[3]));
  smax = fmaxf(smax, 1e-20f);
  const float inv = 127.f / smax;

  int4v o;
#define Q4(V, G) o[G] = ((int)rintf(V.x * inv) & 255) | (((int)rintf(V.y * inv) & 255) << 8) | \
                        (((int)rintf(V.z * inv) & 255) << 16) | (((int)rintf(V.w * inv) & 255) << 24)
  Q4(v0, 0); Q4(v1, 1); Q4(v2, 2); Q4(v3, 3);
#undef Q4
  ((int4v*)(xq + (size_t)row * K_DIM))[tid] = o;
  if (tid == 0) sx[row] = smax / 127.f;
}

// ---- W pack: int32 (0..15) -> i8, 16 elems/thread ----
__global__ __launch_bounds__(256) void pack_w(const int* __restrict__ in,
                                              signed char* __restrict__ wq) {
  const int idx = blockIdx.x * 256 + threadIdx.x;
  const int4* in4 = (const int4*)in + (size_t)idx * 4;
  int4 a = in4[0], b = in4[1], c = in4[2], d = in4[3];
  int4v o;
  o[0] = a.x | (a.y << 8) | (a.z << 16) | (a.w << 24);
  o[1] = b.x | (b.y << 8) | (b.z << 16) | (b.w << 24);
  o[2] = c.x | (c.y << 8) | (c.z << 16) | (c.w << 24);
  o[3] = d.x | (d.y << 8) | (d.z << 16) | (d.w << 24);
  ((int4v*)wq)[idx] = o;
}

// Stage one 64-row x 64-B group (4 KiB, 256 thr x 16 B): linear LDS dest,
// inverse-swizzled global source (rule #21). key(r) = ((r>>1)^(r>>3))&3.
__device__ __forceinline__ void stage_q(const signed char* __restrict__ P,
                                        int grow0, int k0b, char* dest, int tid) {
  const int rl = tid >> 2;                           // 0..63
  const int key = ((rl >> 1) ^ (rl >> 3)) & 3;
  const int kb = (((tid & 3) ^ key) << 4);           // pre-swizzled chunk byte
  async_copy16(&P[(size_t)(grow0 + rl) * K_DIM + k0b + kb], dest + tid * 16);
}

// ---- main GEMM: 128x128 block-tile, 4 waves (2x2, 64x64/wave), BKB=64,
// dbuf 32 KiB => 4 blocks/CU. R5/R12 sync skeleton: prefetch at tile top
// (spread over kq halves), vmcnt(0)+barrier at bottom. Narrow 4-wave sync
// domains; 4 independent blocks fill each other's stalls.
// C/D: col=lane&31, row=(reg&3)+8*(reg>>2)+4*(lane>>5) [R9-R19 HW-ok]. ----
__global__ __launch_bounds__(256, 4) void gemm_i8(
    const signed char* __restrict__ A, const signed char* __restrict__ B,
    const float* __restrict__ scale, const float* __restrict__ sx,
    float* __restrict__ out) {
  __shared__ __align__(16) char smw[2 * BUF_STRIDE];  // 32 KiB
  const int tid = threadIdx.x;
  const int lane = tid & 63;
  const int wv = tid >> 6;
  const int wr = wv >> 1, wc = wv & 1;   // 2x2 wave grid, 64x64 out/wave
  const int l31 = lane & 31;
  const int h = lane >> 5;
  const int swz = ((((l31 >> 1) ^ (l31 >> 3)) & 3) << 4);  // lane-only key

  int id = blockIdx.x;                   // T1: bijective XCD swizzle
  id = (id & 7) * (NWG / 8) + (id >> 3);
  const int bn = (id % NBN) * BN;
  const int bm = (id / NBN) * BM;

  int16v acc[2][2] = {};                 // 64 accum regs

  // prologue: stage tile 0 (4 calls); vmcnt BEFORE barrier (visibility)
  stage_q(A, bm,      0, smw,                tid);
  stage_q(A, bm + 64, 0, smw + 4096,         tid);
  stage_q(B, bn,      0, smw + B_OFF,        tid);
  stage_q(B, bn + 64, 0, smw + B_OFF + 4096, tid);
  asm volatile("s_waitcnt vmcnt(0)" ::: "memory");
  __builtin_amdgcn_s_barrier();

#pragma unroll 1
  for (int t = 0; t < NT; ++t) {
    const int cur = t & 1;
    const char* Abuf = smw + cur * BUF_STRIDE + wr * 4096;  // wave's 64 A-rows
    const char* Bbuf = smw + cur * BUF_STRIDE + B_OFF + wc * 4096;
    char* nb = smw + (cur ^ 1) * BUF_STRIDE;
    const int k1 = (t + 1) * BKB;
    const bool pf = (t + 1 < NT);

    // 2 K-halves; 4 ds_read_b128 + 4 MFMA each; prefetch spread across them
#pragma unroll
    for (int kq = 0; kq < 2; ++kq) {
      const int cb = ((kq * 2 + h) << 4) ^ swz;
      int4v af[2], bfr[2];
#pragma unroll
      for (int mi = 0; mi < 2; ++mi)
        af[mi] = *(const int4v*)(Abuf + (mi * 32 + l31) * 64 + cb);
#pragma unroll
      for (int ni = 0; ni < 2; ++ni)
        bfr[ni] = *(const int4v*)(Bbuf + (ni * 32 + l31) * 64 + cb);
      if (pf) {
        if (kq == 0) {
          stage_q(A, bm,      k1, nb,        tid);
          stage_q(A, bm + 64, k1, nb + 4096, tid);
        } else {
          stage_q(B, bn,      k1, nb + B_OFF,        tid);
          stage_q(B, bn + 64, k1, nb + B_OFF + 4096, tid);
        }
      }
      __builtin_amdgcn_s_setprio(1);
#pragma unroll
      for (int mi = 0; mi < 2; ++mi)
#pragma unroll
        for (int ni = 0; ni < 2; ++ni)
          acc[mi][ni] = __builtin_amdgcn_mfma_i32_32x32x32_i8(
              af[mi], bfr[ni], acc[mi][ni], 0, 0, 0);
      __builtin_amdgcn_s_setprio(0);
    }

    // Bottom sync: drain own prefetch, THEN barrier (cross-wave visibility).
    // Only 4 waves to align; other 3 resident blocks fill the gap.
    if (pf) {
      asm volatile("s_waitcnt vmcnt(0)" ::: "memory");
      __builtin_amdgcn_s_barrier();
    }
  }

  // epilogue: y = acc * sx[row] * scale[col]; 32x32 C/D layout
  const int ocol0 = bn + wc * 64 + l31;
  const int orow0 = bm + wr * 64 + 4 * h;
#pragma unroll
  for (int ni = 0; ni < 2; ++ni) {
    const float sc = scale[ocol0 + ni * 32];
#pragma unroll
    for (int mi = 0; mi < 2; ++mi) {
#pragma unroll
      for (int reg = 0; reg < 16; ++reg) {
        const int row = orow0 + mi * 32 + (reg & 3) + 8 * (reg >> 2);
        out[(size_t)row * N_DIM + ocol0 + ni * 32] =
            (float)acc[mi][ni][reg] * sx[row] * sc;
      }
    }
  }
}

// ---- fallback (only if ws too small): fp32 LDS-tiled, correct but slow ----
__global__ __launch_bounds__(256) void gemm_fallback(
    const float* __restrict__ X, const int* __restrict__ Wq,
    const float* __restrict__ scale, float* __restrict__ out) {
  __shared__ float Xs[64][17];
  __shared__ float Ws[64][17];
  const int tid = threadIdx.x;
  const int tn = blockIdx.x % (N_DIM / 64);
  const int tm = blockIdx.x / (N_DIM / 64);
  const int tr = tid >> 4, tc = tid & 15;
  float acc[4][4] = {};
  for (int k0 = 0; k0 < K_DIM; k0 += 16) {
#pragma unroll
    for (int i = 0; i < 4; ++i) {
      int idx = tid + i * 256;
      int r = idx >> 4, c = idx & 15;
      Xs[r][c] = X[(size_t)(tm * 64 + r) * K_DIM + k0 + c];
      Ws[r][c] = (float)Wq[(size_t)(tn * 64 + r) * K_DIM + k0 + c];
    }
    __syncthreads();
#pragma unroll
    for (int kk = 0; kk < 16; ++kk)
#pragma unroll
      for (int i = 0; i < 4; ++i) {
        float a = Xs[tr * 4 + i][kk];
#pragma unroll
        for (int j = 0; j < 4; ++j) acc[i][j] += a * Ws[tc * 4 + j][kk];
      }
    __syncthreads();
  }
#pragma unroll
  for (int i = 0; i < 4; ++i)
#pragma unroll
    for (int j = 0; j < 4; ++j) {
      int row = tm * 64 + tr * 4 + i, col = tn * 64 + tc * 4 + j;
      out[(size_t)row * N_DIM + col] = acc[i][j] * scale[col];
    }
}

extern "C" void kernel_launch(void* const* d_in, const int* in_sizes, int n_in,
                              void* d_out, int out_size, void* d_ws, size_t ws_size,
                              hipStream_t stream) {
  const float* x = (const float*)d_in[0];
  const int* Wq = (const int*)d_in[1];
  const float* scale = (const float*)d_in[2];
  float* out = (float*)d_out;

  const size_t XN = (size_t)M_DIM * K_DIM;   // 33,554,432
  const size_t WN = (size_t)N_DIM * K_DIM;   // 45,088,768
  const size_t need = XN + WN + M_DIM * sizeof(float);

  if (ws_size >= need) {
    signed char* xq = (signed char*)d_ws;
    signed char* wq = xq + XN;
    float* sx = (float*)(wq + WN);
    quant_x<<<M_DIM, 256, 0, stream>>>(x, xq, sx);
    pack_w<<<(unsigned)(WN / 4096), 256, 0, stream>>>(Wq, wq);
    gemm_i8<<<NWG, 256, 0, stream>>>(xq, wq, scale, sx, out);
  } else {
    gemm_fallback<<<(N_DIM / 64) * (M_DIM / 64), 256, 0, stream>>>(x, Wq, scale, out);
  }
}

// Round 21
// 475.099 us; speedup vs baseline: 1.2102x; 1.2102x over previous
//
#include <hip/hip_runtime.h>
#include <math.h>

// QLinear via int8: y = (sum_k xq[r][k]*Wq[c][k]) * sx[r] * scale[c]
// m201-faithful 8-phase schedule at byte-identical geometry (i8 BKB=128).
// SESSION CHAMPION (R19): gemm ~420 us, total ~480 us, absmax 28.
#define M_DIM 8192
#define N_DIM 11008
#define K_DIM 4096

#define BM 256
#define BN 256
#define BKB 128                    // K-bytes per tile (8 chunks of 16B)
#define NT (K_DIM / BKB)           // 32 K-tiles
#define NBN (N_DIM / BN)           // 43
#define NWG ((M_DIM / BM) * NBN)   // 1376 (divisible by 8)

typedef int int4v __attribute__((ext_vector_type(4)));
typedef int int16v __attribute__((ext_vector_type(16)));

__device__ __forceinline__ void async_copy16(const void* g, void* l) {
  __builtin_amdgcn_global_load_lds(
      (const __attribute__((address_space(1))) void*)g,
      (__attribute__((address_space(3))) void*)l, 16, 0, 0);
}

// ---- x quantization: one block per row; per-row absmax -> i8 (row-major) ----
__global__ __launch_bounds__(256) void quant_x(const float* __restrict__ x,
                                               signed char* __restrict__ xq,
                                               float* __restrict__ sx) {
  __shared__ float wred[4];
  const int row = blockIdx.x;
  const int tid = threadIdx.x;
  const float4* src = (const float4*)(x + (size_t)row * K_DIM) + tid * 4;
  float4 v0 = src[0], v1 = src[1], v2 = src[2], v3 = src[3];

  float m = 0.f;
#define MX4(V) m = fmaxf(m, fmaxf(fmaxf(fabsf(V.x), fabsf(V.y)), fmaxf(fabsf(V.z), fabsf(V.w))))
  MX4(v0); MX4(v1); MX4(v2); MX4(v3);
#undef MX4
#pragma unroll
  for (int off = 32; off >= 1; off >>= 1)
    m = fmaxf(m, __shfl_xor(m, off, 64));
  if ((tid & 63) == 0) wred[tid >> 6] = m;
  __syncthreads();
  float smax = fmaxf(fmaxf(wred[0], wred[1]), fmaxf(wred[2], wred[3]));
  smax = fmaxf(smax, 1e-20f);
  const float inv = 127.f / smax;

  int4v o;
#define Q4(V, G) o[G] = ((int)rintf(V.x * inv) & 255) | (((int)rintf(V.y * inv) & 255) << 8) | \
                        (((int)rintf(V.z * inv) & 255) << 16) | (((int)rintf(V.w * inv) & 255) << 24)
  Q4(v0, 0); Q4(v1, 1); Q4(v2, 2); Q4(v3, 3);
#undef Q4
  ((int4v*)(xq + (size_t)row * K_DIM))[tid] = o;
  if (tid == 0) sx[row] = smax / 127.f;
}

// ---- W pack: int32 (0..15) -> i8 row-major ----
__global__ __launch_bounds__(256) void pack_w(const int* __restrict__ in,
                                              signed char* __restrict__ wq) {
  const int idx = blockIdx.x * 256 + threadIdx.x;
  const int4* in4 = (const int4*)in + (size_t)idx * 4;
  int4 a = in4[0], b = in4[1], c = in4[2], d = in4[3];
  int4v o;
  o[0] = a.x | (a.y << 8) | (a.z << 16) | (a.w << 24);
  o[1] = b.x | (b.y << 8) | (b.z << 16) | (b.w << 24);
  o[2] = c.x | (c.y << 8) | (c.z << 16) | (c.w << 24);
  o[3] = d.x | (d.y << 8) | (d.z << 16) | (d.w << 24);
  ((int4v*)wq)[idx] = o;
}

// Stage one 64-row x 128-B half (8 KiB): linear LDS dest, inverse-swizzled
// global source (rule #21). key(r) = (r&7)^((r>>4)&1) — zero-conflict at
// 128-B rows (R15-measured). 1 gload_lds/thread.
__device__ __forceinline__ void stage_h(const signed char* __restrict__ P,
                                        int grow0, int kbyte, char* dest, int tid) {
  const int rl = tid >> 3;                            // 0..63
  const int key = (rl & 7) ^ ((rl >> 4) & 1);
  const int c = (tid & 7) ^ key;                      // pre-swizzled chunk
  async_copy16(&P[(size_t)(grow0 + rl) * K_DIM + kbyte + c * 16], dest + tid * 16);
}

// ---- main GEMM: 256x256, BKB=128, 8 waves (2x4, 128x64/wave), 2-dbuf
// 128 KiB, m201 8-phase schedule (4 phases/K-tile, 8 MFMA each).
// Phase: {ds_reads | 2 stage gload_lds | bar | lgkm(0)+schedbar | setprio
// 8 MFMA setprio | [vmcnt(2)] | bar}.  Stage order B0B1|B2B3|A0A2|A1A3
// matches first-read order; vmcnt(2)@P1-end certs A1A3(t) (read at P2),
// vmcnt(2)@P4-end certs B*,A0,A2(t+1) (read at P1(t+1)). Never 0 in loop.
// C/D: col=lane&31, row=(reg&3)+8*(reg>>2)+4*(lane>>5) [R9-R19 HW-ok]. ----
__global__ __launch_bounds__(512, 1) void gemm_i8(
    const signed char* __restrict__ A, const signed char* __restrict__ B,
    const float* __restrict__ scale, const float* __restrict__ sx,
    float* __restrict__ out) {
  __shared__ __align__(16) char smw[131072];  // 2 x 64 KiB
  const int tid = threadIdx.x;
  const int lane = tid & 63;
  const int wv = tid >> 6;
  const int wr = wv >> 2, wc = wv & 3;   // 2x4 grid, 128x64 out/wave
  const int l31 = lane & 31;
  const int h = lane >> 5;
  const int keyL = (l31 & 7) ^ ((l31 >> 4) & 1);  // read-side key

  int id = blockIdx.x;                   // T1: bijective XCD swizzle
  id = (id & 7) * (NWG / 8) + (id >> 3);
  const int bn = (id % NBN) * BN;
  const int bm = (id / NBN) * BM;

  int16v acc[4][2] = {};                 // 128 accum regs

#define RD_A(DST, BASE, KS, MIA)                                              \
  DST = *(const int4v*)((BASE) + (wr * 2 + ((MIA) >> 1)) * 8192 +             \
                        (((MIA) & 1) * 32 + l31) * 128 +                      \
                        (((2 * (KS) + h) ^ keyL) << 4));
#define RD_B(DST, BASE, KS, NN)                                               \
  DST = *(const int4v*)((BASE) + 32768 + wc * 8192 +                          \
                        ((NN) * 32 + l31) * 128 +                             \
                        (((2 * (KS) + h) ^ keyL) << 4));

  // prologue: tile0 in order B0,B1,B2,B3,A0,A2,A1,A3 -> buf0; vmcnt(2)
  // leaves A1,A3(0) (first read at P2(0), certed by P1(0)'s vmcnt(2)).
  stage_h(B, bn,       0, smw + 32768, tid);
  stage_h(B, bn +  64, 0, smw + 40960, tid);
  stage_h(B, bn + 128, 0, smw + 49152, tid);
  stage_h(B, bn + 192, 0, smw + 57344, tid);
  stage_h(A, bm,       0, smw,         tid);
  stage_h(A, bm + 128, 0, smw + 16384, tid);
  stage_h(A, bm +  64, 0, smw +  8192, tid);
  stage_h(A, bm + 192, 0, smw + 24576, tid);
  asm volatile("s_waitcnt vmcnt(2)" ::: "memory");
  __builtin_amdgcn_s_barrier();

  int4v aA[2][2], aB[2][2], bL[2][2], bH[2][2];

#pragma unroll 1
  for (int t = 0; t < NT; ++t) {
    const char* cb = smw + (t & 1) * 65536;
    char* nb = smw + ((t + 1) & 1) * 65536;
    const int k1 = (t + 1) * BKB;
    const bool pf = (t + 1 < NT);

    // ---- P1 ----
#pragma unroll
    for (int s = 0; s < 2; ++s)
#pragma unroll
      for (int i = 0; i < 2; ++i) { RD_A(aA[s][i], cb, s, i); }
#pragma unroll
    for (int s = 0; s < 2; ++s)
#pragma unroll
      for (int n = 0; n < 2; ++n) { RD_B(bL[s][n], cb, s, n); }
    if (pf) { stage_h(B, bn, k1, nb + 32768, tid);
              stage_h(B, bn + 64, k1, nb + 40960, tid); }
    __builtin_amdgcn_s_barrier();
    asm volatile("s_waitcnt lgkmcnt(0)" ::: "memory");
    __builtin_amdgcn_sched_barrier(0);
    __builtin_amdgcn_s_setprio(1);
#pragma unroll
    for (int s = 0; s < 2; ++s)
#pragma unroll
      for (int i = 0; i < 2; ++i)
#pragma unroll
        for (int n = 0; n < 2; ++n)
          acc[i][n] = __builtin_amdgcn_mfma_i32_32x32x32_i8(
              aA[s][i], bL[s][n], acc[i][n], 0, 0, 0);
    __builtin_amdgcn_s_setprio(0);
    if (pf) asm volatile("s_waitcnt vmcnt(2)" ::: "memory");
    else    asm volatile("s_waitcnt vmcnt(0)" ::: "memory");
    __builtin_amdgcn_s_barrier();

    // ---- P2 ----
#pragma unroll
    for (int s = 0; s < 2; ++s)
#pragma unroll
      for (int i = 0; i < 2; ++i) { RD_A(aB[s][i], cb, s, i + 2); }
    if (pf) { stage_h(B, bn + 128, k1, nb + 49152, tid);
              stage_h(B, bn + 192, k1, nb + 57344, tid); }
    __builtin_amdgcn_s_barrier();
    asm volatile("s_waitcnt lgkmcnt(0)" ::: "memory");
    __builtin_amdgcn_sched_barrier(0);
    __builtin_amdgcn_s_setprio(1);
#pragma unroll
    for (int s = 0; s < 2; ++s)
#pragma unroll
      for (int i = 0; i < 2; ++i)
#pragma unroll
        for (int n = 0; n < 2; ++n)
          acc[i + 2][n] = __builtin_amdgcn_mfma_i32_32x32x32_i8(
              aB[s][i], bL[s][n], acc[i + 2][n], 0, 0, 0);
    __builtin_amdgcn_s_setprio(0);
    __builtin_amdgcn_s_barrier();

    // ---- P3 ----
#pragma unroll
    for (int s = 0; s < 2; ++s)
#pragma unroll
      for (int i = 0; i < 2; ++i) { RD_A(aA[s][i], cb, s + 2, i); }
#pragma unroll
    for (int s = 0; s < 2; ++s)
#pragma unroll
      for (int n = 0; n < 2; ++n) { RD_B(bH[s][n], cb, s + 2, n); }
    if (pf) { stage_h(A, bm, k1, nb, tid);
              stage_h(A, bm + 128, k1, nb + 16384, tid); }
    __builtin_amdgcn_s_barrier();
    asm volatile("s_waitcnt lgkmcnt(0)" ::: "memory");
    __builtin_amdgcn_sched_barrier(0);
    __builtin_amdgcn_s_setprio(1);
#pragma unroll
    for (int s = 0; s < 2; ++s)
#pragma unroll
      for (int i = 0; i < 2; ++i)
#pragma unroll
        for (int n = 0; n < 2; ++n)
          acc[i][n] = __builtin_amdgcn_mfma_i32_32x32x32_i8(
              aA[s][i], bH[s][n], acc[i][n], 0, 0, 0);
    __builtin_amdgcn_s_setprio(0);
    __builtin_amdgcn_s_barrier();

    // ---- P4 ----
#pragma unroll
    for (int s = 0; s < 2; ++s)
#pragma unroll
      for (int i = 0; i < 2; ++i) { RD_A(aB[s][i], cb, s + 2, i + 2); }
    if (pf) { stage_h(A, bm + 64, k1, nb + 8192, tid);
              stage_h(A, bm + 192, k1, nb + 24576, tid); }
    __builtin_amdgcn_s_barrier();
    asm volatile("s_waitcnt lgkmcnt(0)" ::: "memory");
    __builtin_amdgcn_sched_barrier(0);
    __builtin_amdgcn_s_setprio(1);
#pragma unroll
    for (int s = 0; s < 2; ++s)
#pragma unroll
      for (int i = 0; i < 2; ++i)
#pragma unroll
        for (int n = 0; n < 2; ++n)
          acc[i + 2][n] = __builtin_amdgcn_mfma_i32_32x32x32_i8(
              aB[s][i], bH[s][n], acc[i + 2][n], 0, 0, 0);
    __builtin_amdgcn_s_setprio(0);
    if (pf) {
      asm volatile("s_waitcnt vmcnt(2)" ::: "memory");
      __builtin_amdgcn_s_barrier();
    }
  }

  // epilogue: y = acc * sx[row] * scale[col]; 32x32 C/D layout
  const int ocol0 = bn + wc * 64 + l31;
  const int orow0 = bm + wr * 128 + 4 * h;
#pragma unroll
  for (int ni = 0; ni < 2; ++ni) {
    const float sc = scale[ocol0 + ni * 32];
#pragma unroll
    for (int mi = 0; mi < 4; ++mi) {
#pragma unroll
      for (int reg = 0; reg < 16; ++reg) {
        const int row = orow0 + mi * 32 + (reg & 3) + 8 * (reg >> 2);
        out[(size_t)row * N_DIM + ocol0 + ni * 32] =
            (float)acc[mi][ni][reg] * sx[row] * sc;
      }
    }
  }
#undef RD_A
#undef RD_B
}

// ---- fallback (only if ws too small): fp32 LDS-tiled, correct but slow ----
__global__ __launch_bounds__(256) void gemm_fallback(
    const float* __restrict__ X, const int* __restrict__ Wq,
    const float* __restrict__ scale, float* __restrict__ out) {
  __shared__ float Xs[64][17];
  __shared__ float Ws[64][17];
  const int tid = threadIdx.x;
  const int tn = blockIdx.x % (N_DIM / 64);
  const int tm = blockIdx.x / (N_DIM / 64);
  const int tr = tid >> 4, tc = tid & 15;
  float acc[4][4] = {};
  for (int k0 = 0; k0 < K_DIM; k0 += 16) {
#pragma unroll
    for (int i = 0; i < 4; ++i) {
      int idx = tid + i * 256;
      int r = idx >> 4, c = idx & 15;
      Xs[r][c] = X[(size_t)(tm * 64 + r) * K_DIM + k0 + c];
      Ws[r][c] = (float)Wq[(size_t)(tn * 64 + r) * K_DIM + k0 + c];
    }
    __syncthreads();
#pragma unroll
    for (int kk = 0; kk < 16; ++kk)
#pragma unroll
      for (int i = 0; i < 4; ++i) {
        float a = Xs[tr * 4 + i][kk];
#pragma unroll
        for (int j = 0; j < 4; ++j) acc[i][j] += a * Ws[tc * 4 + j][kk];
      }
    __syncthreads();
  }
#pragma unroll
  for (int i = 0; i < 4; ++i)
#pragma unroll
    for (int j = 0; j < 4; ++j) {
      int row = tm * 64 + tr * 4 + i, col = tn * 64 + tc * 4 + j;
      out[(size_t)row * N_DIM + col] = acc[i][j] * scale[col];
    }
}

extern "C" void kernel_launch(void* const* d_in, const int* in_sizes, int n_in,
                              void* d_out, int out_size, void* d_ws, size_t ws_size,
                              hipStream_t stream) {
  const float* x = (const float*)d_in[0];
  const int* Wq = (const int*)d_in[1];
  const float* scale = (const float*)d_in[2];
  float* out = (float*)d_out;

  const size_t XN = (size_t)M_DIM * K_DIM;   // 33,554,432
  const size_t WN = (size_t)N_DIM * K_DIM;   // 45,088,768
  const size_t need = XN + WN + M_DIM * sizeof(float);

  if (ws_size >= need) {
    signed char* xq = (signed char*)d_ws;
    signed char* wq = xq + XN;
    float* sx = (float*)(wq + WN);
    quant_x<<<M_DIM, 256, 0, stream>>>(x, xq, sx);
    pack_w<<<(unsigned)(WN / 4096), 256, 0, stream>>>(Wq, wq);
    gemm_i8<<<NWG, 512, 0, stream>>>(xq, wq, scale, sx, out);
  } else {
    gemm_fallback<<<(N_DIM / 64) * (M_DIM / 64), 256, 0, stream>>>(x, Wq, scale, out);
  }
}